// Round 7
// baseline (249.416 us; speedup 1.0000x reference)
//
#include <hip/hip_runtime.h>

typedef short bf16x8_t __attribute__((ext_vector_type(8)));
typedef short bf16x4_t __attribute__((ext_vector_type(4)));
typedef float f32x4_t __attribute__((ext_vector_type(4)));

#define B_DIM 4096
#define Q_DIM 256
#define D_DIM 512
#define H_DIM 1024
#define O_DIM 512
#define E_NUM 16
#define K_TOP 4

#define BM 128
#define BN 128
#define BK 32  // per sub-tile; K-step is 2*BK = 64

__device__ __forceinline__ short f2bf(float f) {
  unsigned int u = __float_as_uint(f);
  u += 0x7FFFu + ((u >> 16) & 1u);  // round-to-nearest-even
  return (short)(u >> 16);
}

// async global->LDS, 16B per lane; LDS dest wave-uniform base, lane i -> base+i*16
__device__ __forceinline__ void g2l16(const void* g, void* l) {
  __builtin_amdgcn_global_load_lds(
      (const __attribute__((address_space(1))) void*)(unsigned long long)(size_t)g,
      (__attribute__((address_space(3))) void*)(unsigned)(size_t)l, 16, 0, 0);
}

// ---------------- 64x64 transpose tile: src[R][C] f32 -> dst[C][R] bf16, vector stores
__device__ __forceinline__ void tr_tile(float (*tile)[65], const float* __restrict__ s,
                                        short* __restrict__ d, int R, int C, int r0, int c0,
                                        int t) {
#pragma unroll
  for (int i = 0; i < 16; i++) {
    int lin = i * 256 + t;
    int rr = lin >> 6, cc = lin & 63;
    tile[rr][cc] = s[(size_t)(r0 + rr) * C + (c0 + cc)];
  }
  __syncthreads();
#pragma unroll
  for (int i = 0; i < 2; i++) {
    int task = i * 256 + t;
    int cr = task >> 3, g = task & 7;
    bf16x8_t v;
#pragma unroll
    for (int j = 0; j < 8; j++) v[j] = f2bf(tile[g * 8 + j][cr]);
    *(bf16x8_t*)(d + (size_t)(c0 + cr) * R + r0 + g * 8) = v;
  }
}

// ---------------- merged prep+gating: blocks 0..1023 gating (+x_bf emit),
// 1024..3071 W1 transpose, 3072..5119 W2 transpose. One dispatch -> overlap.
__global__ __launch_bounds__(256) void prep_gate_kernel(
    const float* __restrict__ x, const float* __restrict__ query,
    const float* __restrict__ wg, const float* __restrict__ tg,
    const float* __restrict__ W1, const float* __restrict__ W2,
    short* __restrict__ w1t, short* __restrict__ w2t, short* __restrict__ x_bf,
    int4* __restrict__ topk_e4, float4* __restrict__ topk_g4) {
  __shared__ __align__(16) float smem[12288];  // 48 KB: gate weights OR transpose tile
  const int blk = blockIdx.x, t = threadIdx.x;

  if (blk >= 1024) {  // transposes
    float(*tile)[65] = (float(*)[65])smem;
    if (blk < 3072) {  // W1: [E][512][1024] -> w1t [E][1024][512]
      int b = blk - 1024;
      int e = b >> 7, rem = b & 127;
      int r0 = (rem >> 4) * 64, c0 = (rem & 15) * 64;
      tr_tile(tile, W1 + (size_t)e * D_DIM * H_DIM, w1t + (size_t)e * D_DIM * H_DIM,
              D_DIM, H_DIM, r0, c0, t);
    } else {  // W2: [E][1024][512] -> w2t [E][512][1024]
      int b = blk - 3072;
      int e = b >> 7, rem = b & 127;
      int r0 = (rem >> 3) * 64, c0 = (rem & 7) * 64;
      tr_tile(tile, W2 + (size_t)e * H_DIM * O_DIM, w2t + (size_t)e * H_DIM * O_DIM,
              H_DIM, O_DIM, r0, c0, t);
    }
    return;
  }

  // ---- gating: build s_w[e][768] = [wg[:,e] | tg[:,e]] from raw layout
#pragma unroll
  for (int i = 0; i < 12; i++) {
    int idx4 = (i * 256 + t) * 4;
    if (idx4 < D_DIM * E_NUM) {
      float4 v = *(const float4*)(wg + idx4);
      int d = idx4 >> 4, e0 = idx4 & 15;
      smem[(e0 + 0) * 768 + d] = v.x;
      smem[(e0 + 1) * 768 + d] = v.y;
      smem[(e0 + 2) * 768 + d] = v.z;
      smem[(e0 + 3) * 768 + d] = v.w;
    } else {
      int l2 = idx4 - D_DIM * E_NUM;
      float4 v = *(const float4*)(tg + l2);
      int q = l2 >> 4, e0 = l2 & 15;
      smem[(e0 + 0) * 768 + 512 + q] = v.x;
      smem[(e0 + 1) * 768 + 512 + q] = v.y;
      smem[(e0 + 2) * 768 + 512 + q] = v.z;
      smem[(e0 + 3) * 768 + 512 + q] = v.w;
    }
  }
  __syncthreads();

  const int wv = t >> 6, lane = t & 63;
  const int row = blk * 4 + wv;
  const float4* xr = (const float4*)(x + (size_t)row * D_DIM);
  const float4* qr = (const float4*)(query + (size_t)row * Q_DIM);
  const float4 xv0 = xr[lane], xv1 = xr[64 + lane], qv = qr[lane];

  {  // emit bf16 x row (coalesced 8B stores)
    bf16x4_t v0, v1;
    v0[0] = f2bf(xv0.x); v0[1] = f2bf(xv0.y); v0[2] = f2bf(xv0.z); v0[3] = f2bf(xv0.w);
    v1[0] = f2bf(xv1.x); v1[1] = f2bf(xv1.y); v1[2] = f2bf(xv1.z); v1[3] = f2bf(xv1.w);
    short* xb = x_bf + (size_t)row * D_DIM;
    *(bf16x4_t*)(xb + lane * 4) = v0;
    *(bf16x4_t*)(xb + 256 + lane * 4) = v1;
  }

  const float4* s_w4 = (const float4*)smem;
  float p[E_NUM];
#pragma unroll
  for (int e = 0; e < E_NUM; e++) {
    float4 w0 = s_w4[e * 192 + lane];
    float4 w1 = s_w4[e * 192 + 64 + lane];
    float4 wq = s_w4[e * 192 + 128 + lane];
    p[e] = xv0.x * w0.x + xv0.y * w0.y + xv0.z * w0.z + xv0.w * w0.w +
           xv1.x * w1.x + xv1.y * w1.y + xv1.z * w1.z + xv1.w * w1.w +
           qv.x * wq.x + qv.y * wq.y + qv.z * wq.z + qv.w * wq.w;
  }
#pragma unroll
  for (int e = 0; e < E_NUM; e++) {
    p[e] += __shfl_xor(p[e], 16, 64);
    p[e] += __shfl_xor(p[e], 32, 64);
  }
  // fold e-dimension over lane bits 3..0; after this, lane l holds e = l & 15
#pragma unroll
  for (int s = 8; s >= 1; s >>= 1) {
    const bool take = (lane & s) != 0;
#pragma unroll
    for (int j = 0; j < s; j++) {
      float keep = take ? p[j + s] : p[j];
      float send = take ? p[j] : p[j + s];
      p[j] = keep + __shfl_xor(send, s, 64);
    }
  }
  const float logit = p[0];
  float v[E_NUM];
#pragma unroll
  for (int i = 0; i < E_NUM; i++) v[i] = __shfl(logit, i, 64);

  if (lane == 0) {
    int idx[K_TOP];
    float val[K_TOP];
    unsigned used = 0;
    for (int k = 0; k < K_TOP; k++) {  // strict '>' => lowest index wins ties
      float best = -3.4e38f;
      int bi = 0;
      for (int i = 0; i < E_NUM; i++)
        if (!(used & (1u << i)) && v[i] > best) { best = v[i]; bi = i; }
      used |= 1u << bi;
      idx[k] = bi;
      val[k] = best;
    }
    float mx = val[0];
    float ex[K_TOP], Z = 0.f;
    for (int k = 0; k < K_TOP; k++) { ex[k] = __expf(val[k] - mx); Z += ex[k]; }
    topk_e4[row] = make_int4(idx[0], idx[1], idx[2], idx[3]);
    topk_g4[row] = make_float4(ex[0] / Z, ex[1] / Z, ex[2] / Z, ex[3] / Z);
  }
}

// ---------------- CSR build: 1 block per expert, deterministic prefix-scan positions.
__global__ __launch_bounds__(256) void csr_kernel(
    const int4* __restrict__ topk_e4, const float4* __restrict__ topk_g4,
    int* __restrict__ count, float* __restrict__ imp_g,
    int* __restrict__ rowlist, int* __restrict__ slotid, float* __restrict__ egate) {
  const int e = blockIdx.x, t = threadIdx.x;
  __shared__ int s_cnt[256];
  __shared__ float s_gs[64];
  int c = 0;
  float gs = 0.f;
#pragma unroll 4
  for (int i = 0; i < 16; i++) {
    int row = t * 16 + i;
    int4 v = topk_e4[row];
    float4 g = topk_g4[row];
    if (v.x == e) { c++; gs += g.x; }
    if (v.y == e) { c++; gs += g.y; }
    if (v.z == e) { c++; gs += g.z; }
    if (v.w == e) { c++; gs += g.w; }
  }
  s_cnt[t] = c;
  float gw = gs;
  for (int off = 32; off >= 1; off >>= 1) gw += __shfl_down(gw, off, 64);
  if ((t & 63) == 0) s_gs[t >> 6] = gw;
  __syncthreads();
  for (int off = 1; off < 256; off <<= 1) {
    int vv = (t >= off) ? s_cnt[t - off] : 0;
    __syncthreads();
    s_cnt[t] += vv;
    __syncthreads();
  }
  int pos = s_cnt[t] - c;
#pragma unroll 4
  for (int i = 0; i < 16; i++) {
    int row = t * 16 + i;
    int4 v = topk_e4[row];
    float4 g = topk_g4[row];
    int ve[4] = {v.x, v.y, v.z, v.w};
    float vg[4] = {g.x, g.y, g.z, g.w};
#pragma unroll
    for (int k = 0; k < K_TOP; k++) {
      if (ve[k] == e) {
        rowlist[e * B_DIM + pos] = row;
        slotid[e * B_DIM + pos] = row * K_TOP + k;
        egate[e * B_DIM + pos] = vg[k];
        pos++;
      }
    }
  }
  if (t == 0) {
    count[e] = s_cnt[255];
    imp_g[e] = s_gs[0] + s_gs[1] + s_gs[2] + s_gs[3];
  }
}

// ---------------- loss (cv^2 ddof=1) + per-expert prefix offsets, parallel preload
__global__ __launch_bounds__(64) void loss_offsets_kernel(
    const int* __restrict__ count, const float* __restrict__ imp_g,
    int* __restrict__ offs, float* __restrict__ out_loss) {
  __shared__ int s_c[E_NUM];
  __shared__ float s_i[E_NUM];
  const int t = threadIdx.x;
  if (t < E_NUM) { s_c[t] = count[t]; s_i[t] = imp_g[t]; }
  __syncthreads();
  if (t == 0) {
    float mi = 0.f, ml = 0.f;
    for (int i = 0; i < E_NUM; i++) { mi += s_i[i]; ml += (float)s_c[i]; }
    mi /= (float)E_NUM;
    ml /= (float)E_NUM;
    float vi = 0.f, vl = 0.f;
    for (int i = 0; i < E_NUM; i++) {
      float di = s_i[i] - mi;
      vi += di * di;
      float dl = (float)s_c[i] - ml;
      vl += dl * dl;
    }
    vi /= (float)(E_NUM - 1);
    vl /= (float)(E_NUM - 1);
    out_loss[0] = 0.01f * (vi / (mi * mi + 1e-10f) + vl / (ml * ml + 1e-10f));
    int run = 0;
    for (int i = 0; i < E_NUM; i++) { offs[i] = run; run += s_c[i]; }
  }
}

// ---------------- GEMM1: h[entry] = relu(x[row] @ W1[e] + b1[e]), bf16 out
// K-step 64 via twin [128][32] tiles: half the barriers, 32 MFMA/wave per barrier.
__global__ __launch_bounds__(256) void gemm1_kernel(
    const short* __restrict__ x_bf, const short* __restrict__ w1t,
    const float* __restrict__ b1, const int* __restrict__ count,
    const int* __restrict__ offs, const int* __restrict__ rowlist,
    short* __restrict__ h_buf) {
  const int flat = blockIdx.x;
  const int xcd = flat & 7, j = flat >> 3;
  const int mt = j & 31, gidx = j >> 5;
  const int group = xcd * 16 + gidx;
  const int e = group >> 3, nt = group & 7;
  const int n_e = count[e];
  if (mt * BM >= n_e) return;
  __shared__ __align__(16) short As0[BM * BK], As1[BM * BK];
  __shared__ __align__(16) short Bs0[BN * BK], Bs1[BN * BK];
  const int t = threadIdx.x, lane = t & 63, wv = t >> 6;
  const int wm = wv >> 1, wn = wv & 1;
  const int srow = wv * 16 + (lane >> 2);  // staging row 0..63
  const int kb = (lane & 3) * 8;           // bf16 elems within 32-elem k-slice
  int gr0 = mt * BM + srow;       gr0 = gr0 < n_e ? gr0 : n_e - 1;
  int gr1 = mt * BM + 64 + srow;  gr1 = gr1 < n_e ? gr1 : n_e - 1;
  const short* pa0 = x_bf + (size_t)rowlist[e * B_DIM + gr0] * D_DIM + kb;
  const short* pa1 = x_bf + (size_t)rowlist[e * B_DIM + gr1] * D_DIM + kb;
  const short* w1te = w1t + ((size_t)e * H_DIM + nt * BN) * D_DIM;
  const short* pb0 = w1te + (size_t)srow * D_DIM + kb;
  const short* pb1 = w1te + (size_t)(64 + srow) * D_DIM + kb;
  const int lo0 = wv * 16 * BK, lo1 = (64 + wv * 16) * BK;

  f32x4_t acc[4][4] = {};
  const int frow = lane & 15, kg = lane >> 4;

  for (int k0 = 0; k0 < D_DIM; k0 += 2 * BK) {
    g2l16(pa0 + k0, As0 + lo0);
    g2l16(pa1 + k0, As0 + lo1);
    g2l16(pb0 + k0, Bs0 + lo0);
    g2l16(pb1 + k0, Bs0 + lo1);
    g2l16(pa0 + k0 + BK, As1 + lo0);
    g2l16(pa1 + k0 + BK, As1 + lo1);
    g2l16(pb0 + k0 + BK, Bs1 + lo0);
    g2l16(pb1 + k0 + BK, Bs1 + lo1);
    __syncthreads();
#pragma unroll
    for (int half = 0; half < 2; half++) {
      const short* A = half ? As1 : As0;
      const short* B = half ? Bs1 : Bs0;
      bf16x8_t af[4], bfr[4];
#pragma unroll
      for (int mi = 0; mi < 4; mi++)
        af[mi] = *(const bf16x8_t*)&A[(wm * 64 + mi * 16 + frow) * BK + kg * 8];
#pragma unroll
      for (int ni = 0; ni < 4; ni++)
        bfr[ni] = *(const bf16x8_t*)&B[(wn * 64 + ni * 16 + frow) * BK + kg * 8];
#pragma unroll
      for (int mi = 0; mi < 4; mi++)
#pragma unroll
        for (int ni = 0; ni < 4; ni++)
          acc[mi][ni] =
              __builtin_amdgcn_mfma_f32_16x16x32_bf16(af[mi], bfr[ni], acc[mi][ni], 0, 0, 0);
    }
    __syncthreads();
  }
  const int obase = offs[e];
#pragma unroll
  for (int mi = 0; mi < 4; mi++) {
#pragma unroll
    for (int r = 0; r < 4; r++) {
      int row = wm * 64 + mi * 16 + kg * 4 + r;
      int m_local = mt * BM + row;
      if (m_local >= n_e) continue;
      size_t hrow = (size_t)(obase + m_local) * H_DIM;
#pragma unroll
      for (int ni = 0; ni < 4; ni++) {
        int col = nt * BN + wn * 64 + ni * 16 + frow;
        float vv = acc[mi][ni][r] + b1[e * H_DIM + col];
        h_buf[hrow + col] = f2bf(vv > 0.f ? vv : 0.f);
      }
    }
  }
}

// ---------------- GEMM2: out_buf[slot] = (h[entry] @ W2[e] + b2[e]) * gate
__global__ __launch_bounds__(256) void gemm2_kernel(
    const short* __restrict__ h_buf, const short* __restrict__ w2t,
    const float* __restrict__ b2, const int* __restrict__ count,
    const int* __restrict__ offs, const int* __restrict__ slotid,
    const float* __restrict__ egate, float* __restrict__ out_buf) {
  const int flat = blockIdx.x;
  const int xcd = flat & 7, j = flat >> 3;
  const int nt = j & 3, gidx = j >> 2;
  const int group = xcd * 64 + gidx;
  const int e = group >> 5, mt = group & 31;
  const int n_e = count[e];
  if (mt * BM >= n_e) return;
  __shared__ __align__(16) short As0[BM * BK], As1[BM * BK];
  __shared__ __align__(16) short Bs0[BN * BK], Bs1[BN * BK];
  const int t = threadIdx.x, lane = t & 63, wv = t >> 6;
  const int wm = wv >> 1, wn = wv & 1;
  const int srow = wv * 16 + (lane >> 2);
  const int kb = (lane & 3) * 8;
  const int obase = offs[e];
  int gr0 = mt * BM + srow;       gr0 = gr0 < n_e ? gr0 : n_e - 1;
  int gr1 = mt * BM + 64 + srow;  gr1 = gr1 < n_e ? gr1 : n_e - 1;
  const short* pa0 = h_buf + (size_t)(obase + gr0) * H_DIM + kb;
  const short* pa1 = h_buf + (size_t)(obase + gr1) * H_DIM + kb;
  const short* w2te = w2t + ((size_t)e * O_DIM + nt * BN) * H_DIM;
  const short* pb0 = w2te + (size_t)srow * H_DIM + kb;
  const short* pb1 = w2te + (size_t)(64 + srow) * H_DIM + kb;
  const int lo0 = wv * 16 * BK, lo1 = (64 + wv * 16) * BK;

  f32x4_t acc[4][4] = {};
  const int frow = lane & 15, kg = lane >> 4;

  for (int k0 = 0; k0 < H_DIM; k0 += 2 * BK) {
    g2l16(pa0 + k0, As0 + lo0);
    g2l16(pa1 + k0, As0 + lo1);
    g2l16(pb0 + k0, Bs0 + lo0);
    g2l16(pb1 + k0, Bs0 + lo1);
    g2l16(pa0 + k0 + BK, As1 + lo0);
    g2l16(pa1 + k0 + BK, As1 + lo1);
    g2l16(pb0 + k0 + BK, Bs1 + lo0);
    g2l16(pb1 + k0 + BK, Bs1 + lo1);
    __syncthreads();
#pragma unroll
    for (int half = 0; half < 2; half++) {
      const short* A = half ? As1 : As0;
      const short* B = half ? Bs1 : Bs0;
      bf16x8_t af[4], bfr[4];
#pragma unroll
      for (int mi = 0; mi < 4; mi++)
        af[mi] = *(const bf16x8_t*)&A[(wm * 64 + mi * 16 + frow) * BK + kg * 8];
#pragma unroll
      for (int ni = 0; ni < 4; ni++)
        bfr[ni] = *(const bf16x8_t*)&B[(wn * 64 + ni * 16 + frow) * BK + kg * 8];
#pragma unroll
      for (int mi = 0; mi < 4; mi++)
#pragma unroll
        for (int ni = 0; ni < 4; ni++)
          acc[mi][ni] =
              __builtin_amdgcn_mfma_f32_16x16x32_bf16(af[mi], bfr[ni], acc[mi][ni], 0, 0, 0);
    }
    __syncthreads();
  }
#pragma unroll
  for (int mi = 0; mi < 4; mi++) {
#pragma unroll
    for (int r = 0; r < 4; r++) {
      int row = wm * 64 + mi * 16 + kg * 4 + r;
      int m_local = mt * BM + row;
      if (m_local >= n_e) continue;
      float g = egate[e * B_DIM + m_local];
      size_t orow = (size_t)slotid[e * B_DIM + m_local] * O_DIM;
#pragma unroll
      for (int ni = 0; ni < 4; ni++) {
        int col = nt * BN + wn * 64 + ni * 16 + frow;
        out_buf[orow + col] = (acc[mi][ni][r] + b2[e * O_DIM + col]) * g;
      }
    }
  }
}

// ---------------- combine: y[b] = sum over 4 slots
__global__ __launch_bounds__(256) void combine_kernel(const float* __restrict__ out_buf,
                                                      float* __restrict__ y) {
  int idx = blockIdx.x * 256 + threadIdx.x;  // B*O/4 threads
  int b = idx >> 7;
  int o = (idx & 127) << 2;
  const float* base = out_buf + (size_t)b * K_TOP * O_DIM + o;
  float4 a0 = *(const float4*)(base);
  float4 a1 = *(const float4*)(base + O_DIM);
  float4 a2 = *(const float4*)(base + 2 * O_DIM);
  float4 a3 = *(const float4*)(base + 3 * O_DIM);
  float4 r;
  r.x = a0.x + a1.x + a2.x + a3.x;
  r.y = a0.y + a1.y + a2.y + a3.y;
  r.z = a0.z + a1.z + a2.z + a3.z;
  r.w = a0.w + a1.w + a2.w + a3.w;
  *(float4*)(y + (size_t)b * O_DIM + o) = r;
}

extern "C" void kernel_launch(void* const* d_in, const int* in_sizes, int n_in,
                              void* d_out, int out_size, void* d_ws, size_t ws_size,
                              hipStream_t stream) {
  (void)in_sizes; (void)n_in; (void)out_size; (void)ws_size;
  const float* query = (const float*)d_in[0];
  const float* x = (const float*)d_in[1];
  const float* wg = (const float*)d_in[2];
  const float* tg = (const float*)d_in[3];
  const float* W1 = (const float*)d_in[4];
  const float* b1 = (const float*)d_in[5];
  const float* W2 = (const float*)d_in[6];
  const float* b2 = (const float*)d_in[7];
  float* y = (float*)d_out;

  char* ws = (char*)d_ws;
  int* count = (int*)(ws + 0);                // 64 B
  float* imp = (float*)(ws + 64);             // 64 B
  int* offs = (int*)(ws + 128);               // 64 B
  int* rowlist = (int*)(ws + 256);            // 256 KB
  int* slotid = (int*)(ws + 262400);          // 256 KB
  float* egate = (float*)(ws + 524544);       // 256 KB
  int4* topk_e4 = (int4*)(ws + 786688);       // 64 KB
  float4* topk_g4 = (float4*)(ws + 852224);   // 64 KB
  short* h_buf = (short*)(ws + 1048576);      // 32 MB bf16 [16384][H]  (live gemm1->gemm2)
  short* w2t = (short*)(ws + 34603008);       // 16 MB bf16 [E][O][H]   (live ->gemm2)
  // region A: dead after gemm1, overlaid by out_buf
  short* x_bf = (short*)(ws + 51380224);      // 4 MB  bf16 [4096][512]
  short* w1t = (short*)(ws + 55574528);       // 16 MB bf16 [E][H][D]
  float* out_buf = (float*)(ws + 51380224);   // 32 MB f32 [16384][O]   (overlays region A)

  prep_gate_kernel<<<dim3(5120), 256, 0, stream>>>(x, query, wg, tg, W1, W2,
                                                   w1t, w2t, x_bf, topk_e4, topk_g4);
  csr_kernel<<<dim3(E_NUM), 256, 0, stream>>>(topk_e4, topk_g4, count, imp,
                                              rowlist, slotid, egate);
  loss_offsets_kernel<<<1, 64, 0, stream>>>(count, imp, offs, y + (size_t)B_DIM * O_DIM);
  gemm1_kernel<<<dim3(4096), 256, 0, stream>>>(x_bf, w1t, b1, count, offs, rowlist, h_buf);
  gemm2_kernel<<<dim3(2048), 256, 0, stream>>>(h_buf, w2t, b2, count, offs, slotid, egate,
                                               out_buf);
  combine_kernel<<<dim3(B_DIM * O_DIM / 4 / 256), 256, 0, stream>>>(out_buf, y);
}

// Round 8
// 236.913 us; speedup vs baseline: 1.0528x; 1.0528x over previous
//
#include <hip/hip_runtime.h>

typedef short bf16x8_t __attribute__((ext_vector_type(8)));
typedef short bf16x4_t __attribute__((ext_vector_type(4)));
typedef float f32x4_t __attribute__((ext_vector_type(4)));

#define B_DIM 4096
#define Q_DIM 256
#define D_DIM 512
#define H_DIM 1024
#define O_DIM 512
#define E_NUM 16
#define K_TOP 4

#define BM 128
#define BN 128
#define BK 32

__device__ __forceinline__ short f2bf(float f) {
  unsigned int u = __float_as_uint(f);
  u += 0x7FFFu + ((u >> 16) & 1u);  // round-to-nearest-even
  return (short)(u >> 16);
}

// async global->LDS, 16B per lane; LDS dest wave-uniform base, lane i -> base+i*16
__device__ __forceinline__ void g2l16(const void* g, void* l) {
  __builtin_amdgcn_global_load_lds(
      (const __attribute__((address_space(1))) void*)(unsigned long long)(size_t)g,
      (__attribute__((address_space(3))) void*)(unsigned)(size_t)l, 16, 0, 0);
}

// ---------------- 64x64 transpose tile: src[R][C] f32 -> dst[C][R] bf16, vector stores
__device__ __forceinline__ void tr_tile(float (*tile)[65], const float* __restrict__ s,
                                        short* __restrict__ d, int R, int C, int r0, int c0,
                                        int t) {
#pragma unroll
  for (int i = 0; i < 16; i++) {
    int lin = i * 256 + t;
    int rr = lin >> 6, cc = lin & 63;
    tile[rr][cc] = s[(size_t)(r0 + rr) * C + (c0 + cc)];
  }
  __syncthreads();
#pragma unroll
  for (int i = 0; i < 2; i++) {
    int task = i * 256 + t;
    int cr = task >> 3, g = task & 7;
    bf16x8_t v;
#pragma unroll
    for (int j = 0; j < 8; j++) v[j] = f2bf(tile[g * 8 + j][cr]);
    *(bf16x8_t*)(d + (size_t)(c0 + cr) * R + r0 + g * 8) = v;
  }
}

// ---------------- merged prep+gating: blocks 0..1023 gating (+x_bf emit),
// 1024..3071 W1 transpose, 3072..5119 W2 transpose.
__global__ __launch_bounds__(256) void prep_gate_kernel(
    const float* __restrict__ x, const float* __restrict__ query,
    const float* __restrict__ wg, const float* __restrict__ tg,
    const float* __restrict__ W1, const float* __restrict__ W2,
    short* __restrict__ w1t, short* __restrict__ w2t, short* __restrict__ x_bf,
    int4* __restrict__ topk_e4, float4* __restrict__ topk_g4) {
  __shared__ __align__(16) float smem[12288];  // 48 KB: gate weights OR transpose tile
  const int blk = blockIdx.x, t = threadIdx.x;

  if (blk >= 1024) {  // transposes
    float(*tile)[65] = (float(*)[65])smem;
    if (blk < 3072) {  // W1: [E][512][1024] -> w1t [E][1024][512]
      int b = blk - 1024;
      int e = b >> 7, rem = b & 127;
      int r0 = (rem >> 4) * 64, c0 = (rem & 15) * 64;
      tr_tile(tile, W1 + (size_t)e * D_DIM * H_DIM, w1t + (size_t)e * D_DIM * H_DIM,
              D_DIM, H_DIM, r0, c0, t);
    } else {  // W2: [E][1024][512] -> w2t [E][512][1024]
      int b = blk - 3072;
      int e = b >> 7, rem = b & 127;
      int r0 = (rem >> 3) * 64, c0 = (rem & 7) * 64;
      tr_tile(tile, W2 + (size_t)e * H_DIM * O_DIM, w2t + (size_t)e * H_DIM * O_DIM,
              H_DIM, O_DIM, r0, c0, t);
    }
    return;
  }

  // ---- gating: build s_w[e][768] = [wg[:,e] | tg[:,e]] from raw layout
#pragma unroll
  for (int i = 0; i < 12; i++) {
    int idx4 = (i * 256 + t) * 4;
    if (idx4 < D_DIM * E_NUM) {
      float4 v = *(const float4*)(wg + idx4);
      int d = idx4 >> 4, e0 = idx4 & 15;
      smem[(e0 + 0) * 768 + d] = v.x;
      smem[(e0 + 1) * 768 + d] = v.y;
      smem[(e0 + 2) * 768 + d] = v.z;
      smem[(e0 + 3) * 768 + d] = v.w;
    } else {
      int l2 = idx4 - D_DIM * E_NUM;
      float4 v = *(const float4*)(tg + l2);
      int q = l2 >> 4, e0 = l2 & 15;
      smem[(e0 + 0) * 768 + 512 + q] = v.x;
      smem[(e0 + 1) * 768 + 512 + q] = v.y;
      smem[(e0 + 2) * 768 + 512 + q] = v.z;
      smem[(e0 + 3) * 768 + 512 + q] = v.w;
    }
  }
  __syncthreads();

  const int wv = t >> 6, lane = t & 63;
  const int row = blk * 4 + wv;
  const float4* xr = (const float4*)(x + (size_t)row * D_DIM);
  const float4* qr = (const float4*)(query + (size_t)row * Q_DIM);
  const float4 xv0 = xr[lane], xv1 = xr[64 + lane], qv = qr[lane];

  {  // emit bf16 x row (coalesced 8B stores)
    bf16x4_t v0, v1;
    v0[0] = f2bf(xv0.x); v0[1] = f2bf(xv0.y); v0[2] = f2bf(xv0.z); v0[3] = f2bf(xv0.w);
    v1[0] = f2bf(xv1.x); v1[1] = f2bf(xv1.y); v1[2] = f2bf(xv1.z); v1[3] = f2bf(xv1.w);
    short* xb = x_bf + (size_t)row * D_DIM;
    *(bf16x4_t*)(xb + lane * 4) = v0;
    *(bf16x4_t*)(xb + 256 + lane * 4) = v1;
  }

  const float4* s_w4 = (const float4*)smem;
  float p[E_NUM];
#pragma unroll
  for (int e = 0; e < E_NUM; e++) {
    float4 w0 = s_w4[e * 192 + lane];
    float4 w1 = s_w4[e * 192 + 64 + lane];
    float4 wq = s_w4[e * 192 + 128 + lane];
    p[e] = xv0.x * w0.x + xv0.y * w0.y + xv0.z * w0.z + xv0.w * w0.w +
           xv1.x * w1.x + xv1.y * w1.y + xv1.z * w1.z + xv1.w * w1.w +
           qv.x * wq.x + qv.y * wq.y + qv.z * wq.z + qv.w * wq.w;
  }
#pragma unroll
  for (int e = 0; e < E_NUM; e++) {
    p[e] += __shfl_xor(p[e], 16, 64);
    p[e] += __shfl_xor(p[e], 32, 64);
  }
  // fold e-dimension over lane bits 3..0; after this, lane l holds e = l & 15
#pragma unroll
  for (int s = 8; s >= 1; s >>= 1) {
    const bool take = (lane & s) != 0;
#pragma unroll
    for (int j = 0; j < s; j++) {
      float keep = take ? p[j + s] : p[j];
      float send = take ? p[j] : p[j + s];
      p[j] = keep + __shfl_xor(send, s, 64);
    }
  }
  const float logit = p[0];
  float v[E_NUM];
#pragma unroll
  for (int i = 0; i < E_NUM; i++) v[i] = __shfl(logit, i, 64);

  if (lane == 0) {
    int idx[K_TOP];
    float val[K_TOP];
    unsigned used = 0;
    for (int k = 0; k < K_TOP; k++) {  // strict '>' => lowest index wins ties
      float best = -3.4e38f;
      int bi = 0;
      for (int i = 0; i < E_NUM; i++)
        if (!(used & (1u << i)) && v[i] > best) { best = v[i]; bi = i; }
      used |= 1u << bi;
      idx[k] = bi;
      val[k] = best;
    }
    float mx = val[0];
    float ex[K_TOP], Z = 0.f;
    for (int k = 0; k < K_TOP; k++) { ex[k] = __expf(val[k] - mx); Z += ex[k]; }
    topk_e4[row] = make_int4(idx[0], idx[1], idx[2], idx[3]);
    topk_g4[row] = make_float4(ex[0] / Z, ex[1] / Z, ex[2] / Z, ex[3] / Z);
  }
}

// ---------------- CSR v3: 16 blocks x 1024 threads, 4 rows/thread. Each block
// computes its own offs[e] (count of entries with expert<e). Block 0 additionally
// computes the loss via LDS-atomic histogram. No loss kernel, no global atomics.
__global__ __launch_bounds__(1024) void csr_kernel(
    const int4* __restrict__ topk_e4, const float4* __restrict__ topk_g4,
    int* __restrict__ count, int* __restrict__ offs,
    int* __restrict__ rowlist, int* __restrict__ slotid, float* __restrict__ egate,
    float* __restrict__ out_loss) {
  const int e = blockIdx.x, t = threadIdx.x;
  __shared__ int s_cnt[1024];
  __shared__ int s_lt[16];
  __shared__ int s_hc[E_NUM];
  __shared__ float s_hi[E_NUM];
  if (e == 0 && t < E_NUM) { s_hc[t] = 0; s_hi[t] = 0.f; }
  __syncthreads();

  int4 v4[4];
  float4 g4[4];
  int c = 0, clt = 0;
#pragma unroll
  for (int i = 0; i < 4; i++) {
    int row = t * 4 + i;
    v4[i] = topk_e4[row];
    g4[i] = topk_g4[row];
    int ve[4] = {v4[i].x, v4[i].y, v4[i].z, v4[i].w};
    float vg[4] = {g4[i].x, g4[i].y, g4[i].z, g4[i].w};
#pragma unroll
    for (int k = 0; k < K_TOP; k++) {
      c += (ve[k] == e);
      clt += (ve[k] < e);
      if (e == 0) {  // block 0: histogram for loss
        atomicAdd(&s_hc[ve[k]], 1);
        atomicAdd(&s_hi[ve[k]], vg[k]);
      }
    }
  }
  s_cnt[t] = c;
  // block-reduce clt: wave shuffle then LDS
  int w = clt;
  for (int off = 32; off >= 1; off >>= 1) w += __shfl_down(w, off, 64);
  if ((t & 63) == 0) s_lt[t >> 6] = w;
  __syncthreads();
  // Hillis-Steele inclusive scan over 1024 counts
  for (int off = 1; off < 1024; off <<= 1) {
    int vv = (t >= off) ? s_cnt[t - off] : 0;
    __syncthreads();
    s_cnt[t] += vv;
    __syncthreads();
  }
  int pos = s_cnt[t] - c;  // exclusive base within expert-e list
#pragma unroll
  for (int i = 0; i < 4; i++) {
    int row = t * 4 + i;
    int ve[4] = {v4[i].x, v4[i].y, v4[i].z, v4[i].w};
    float vg[4] = {g4[i].x, g4[i].y, g4[i].z, g4[i].w};
#pragma unroll
    for (int k = 0; k < K_TOP; k++) {
      if (ve[k] == e) {
        rowlist[e * B_DIM + pos] = row;
        slotid[e * B_DIM + pos] = row * K_TOP + k;
        egate[e * B_DIM + pos] = vg[k];
        pos++;
      }
    }
  }
  if (t == 0) {
    count[e] = s_cnt[1023];
    int base = 0;
    for (int i = 0; i < 16; i++) base += s_lt[i];
    offs[e] = base;
  }
  if (e == 0 && t == 1) {  // loss (cv^2, ddof=1)
    __syncthreads();  // hist done before scan barriers anyway; belt & braces
    float mi = 0.f, ml = 0.f;
    for (int i = 0; i < E_NUM; i++) { mi += s_hi[i]; ml += (float)s_hc[i]; }
    mi /= (float)E_NUM;
    ml /= (float)E_NUM;
    float vi = 0.f, vl = 0.f;
    for (int i = 0; i < E_NUM; i++) {
      float di = s_hi[i] - mi;
      vi += di * di;
      float dl = (float)s_hc[i] - ml;
      vl += dl * dl;
    }
    vi /= (float)(E_NUM - 1);
    vl /= (float)(E_NUM - 1);
    out_loss[0] = 0.01f * (vi / (mi * mi + 1e-10f) + vl / (ml * ml + 1e-10f));
  }
}

// ---------------- GEMM1: h[entry] = relu(x[row] @ W1[e] + b1[e]), bf16 out
// R6-proven: BK=32 single buffer, 16 KB LDS, XCD swizzle grouping mt over (e,nt).
__global__ __launch_bounds__(256) void gemm1_kernel(
    const short* __restrict__ x_bf, const short* __restrict__ w1t,
    const float* __restrict__ b1, const int* __restrict__ count,
    const int* __restrict__ offs, const int* __restrict__ rowlist,
    short* __restrict__ h_buf) {
  const int flat = blockIdx.x;
  const int xcd = flat & 7, j = flat >> 3;
  const int mt = j & 31, gidx = j >> 5;
  const int group = xcd * 16 + gidx;
  const int e = group >> 3, nt = group & 7;
  const int n_e = count[e];
  if (mt * BM >= n_e) return;
  __shared__ __align__(16) short As[BM * BK];
  __shared__ __align__(16) short Bs[BN * BK];
  const int t = threadIdx.x, lane = t & 63, wv = t >> 6;
  const int wm = wv >> 1, wn = wv & 1;
  const int srow = wv * 16 + (lane >> 2);
  const int kb = (lane & 3) * 8;
  int gr0 = mt * BM + srow;       gr0 = gr0 < n_e ? gr0 : n_e - 1;
  int gr1 = mt * BM + 64 + srow;  gr1 = gr1 < n_e ? gr1 : n_e - 1;
  const short* pa0 = x_bf + (size_t)rowlist[e * B_DIM + gr0] * D_DIM + kb;
  const short* pa1 = x_bf + (size_t)rowlist[e * B_DIM + gr1] * D_DIM + kb;
  const short* w1te = w1t + ((size_t)e * H_DIM + nt * BN) * D_DIM;
  const short* pb0 = w1te + (size_t)srow * D_DIM + kb;
  const short* pb1 = w1te + (size_t)(64 + srow) * D_DIM + kb;
  short* lA0 = As + wv * 16 * BK;
  short* lA1 = As + (64 + wv * 16) * BK;
  short* lB0 = Bs + wv * 16 * BK;
  short* lB1 = Bs + (64 + wv * 16) * BK;

  f32x4_t acc[4][4] = {};
  const int frow = lane & 15, kg = lane >> 4;

  for (int k0 = 0; k0 < D_DIM; k0 += BK) {
    g2l16(pa0 + k0, lA0);
    g2l16(pa1 + k0, lA1);
    g2l16(pb0 + k0, lB0);
    g2l16(pb1 + k0, lB1);
    __syncthreads();
    bf16x8_t af[4], bfr[4];
#pragma unroll
    for (int mi = 0; mi < 4; mi++)
      af[mi] = *(const bf16x8_t*)&As[(wm * 64 + mi * 16 + frow) * BK + kg * 8];
#pragma unroll
    for (int ni = 0; ni < 4; ni++)
      bfr[ni] = *(const bf16x8_t*)&Bs[(wn * 64 + ni * 16 + frow) * BK + kg * 8];
#pragma unroll
    for (int mi = 0; mi < 4; mi++)
#pragma unroll
      for (int ni = 0; ni < 4; ni++)
        acc[mi][ni] = __builtin_amdgcn_mfma_f32_16x16x32_bf16(af[mi], bfr[ni], acc[mi][ni], 0, 0, 0);
    __syncthreads();
  }
  const int obase = offs[e];
#pragma unroll
  for (int mi = 0; mi < 4; mi++) {
#pragma unroll
    for (int r = 0; r < 4; r++) {
      int row = wm * 64 + mi * 16 + kg * 4 + r;
      int m_local = mt * BM + row;
      if (m_local >= n_e) continue;
      size_t hrow = (size_t)(obase + m_local) * H_DIM;
#pragma unroll
      for (int ni = 0; ni < 4; ni++) {
        int col = nt * BN + wn * 64 + ni * 16 + frow;
        float vv = acc[mi][ni][r] + b1[e * H_DIM + col];
        h_buf[hrow + col] = f2bf(vv > 0.f ? vv : 0.f);
      }
    }
  }
}

// ---------------- GEMM2: out_buf[slot] = (h[entry] @ W2[e] + b2[e]) * gate
// R6-proven: BK=32 single buffer, XCD swizzle grouping nt over (e,mt).
__global__ __launch_bounds__(256) void gemm2_kernel(
    const short* __restrict__ h_buf, const short* __restrict__ w2t,
    const float* __restrict__ b2, const int* __restrict__ count,
    const int* __restrict__ offs, const int* __restrict__ slotid,
    const float* __restrict__ egate, float* __restrict__ out_buf) {
  const int flat = blockIdx.x;
  const int xcd = flat & 7, j = flat >> 3;
  const int nt = j & 3, gidx = j >> 2;
  const int group = xcd * 64 + gidx;
  const int e = group >> 5, mt = group & 31;
  const int n_e = count[e];
  if (mt * BM >= n_e) return;
  __shared__ __align__(16) short As[BM * BK];
  __shared__ __align__(16) short Bs[BN * BK];
  const int t = threadIdx.x, lane = t & 63, wv = t >> 6;
  const int wm = wv >> 1, wn = wv & 1;
  const int srow = wv * 16 + (lane >> 2);
  const int kb = (lane & 3) * 8;
  const int obase = offs[e];
  int gr0 = mt * BM + srow;       gr0 = gr0 < n_e ? gr0 : n_e - 1;
  int gr1 = mt * BM + 64 + srow;  gr1 = gr1 < n_e ? gr1 : n_e - 1;
  const short* pa0 = h_buf + (size_t)(obase + gr0) * H_DIM + kb;
  const short* pa1 = h_buf + (size_t)(obase + gr1) * H_DIM + kb;
  const short* w2te = w2t + ((size_t)e * O_DIM + nt * BN) * H_DIM;
  const short* pb0 = w2te + (size_t)srow * H_DIM + kb;
  const short* pb1 = w2te + (size_t)(64 + srow) * H_DIM + kb;
  short* lA0 = As + wv * 16 * BK;
  short* lA1 = As + (64 + wv * 16) * BK;
  short* lB0 = Bs + wv * 16 * BK;
  short* lB1 = Bs + (64 + wv * 16) * BK;

  f32x4_t acc[4][4] = {};
  const int frow = lane & 15, kg = lane >> 4;

  for (int k0 = 0; k0 < H_DIM; k0 += BK) {
    g2l16(pa0 + k0, lA0);
    g2l16(pa1 + k0, lA1);
    g2l16(pb0 + k0, lB0);
    g2l16(pb1 + k0, lB1);
    __syncthreads();
    bf16x8_t af[4], bfr[4];
#pragma unroll
    for (int mi = 0; mi < 4; mi++)
      af[mi] = *(const bf16x8_t*)&As[(wm * 64 + mi * 16 + frow) * BK + kg * 8];
#pragma unroll
    for (int ni = 0; ni < 4; ni++)
      bfr[ni] = *(const bf16x8_t*)&Bs[(wn * 64 + ni * 16 + frow) * BK + kg * 8];
#pragma unroll
    for (int mi = 0; mi < 4; mi++)
#pragma unroll
      for (int ni = 0; ni < 4; ni++)
        acc[mi][ni] = __builtin_amdgcn_mfma_f32_16x16x32_bf16(af[mi], bfr[ni], acc[mi][ni], 0, 0, 0);
    __syncthreads();
  }
#pragma unroll
  for (int mi = 0; mi < 4; mi++) {
#pragma unroll
    for (int r = 0; r < 4; r++) {
      int row = wm * 64 + mi * 16 + kg * 4 + r;
      int m_local = mt * BM + row;
      if (m_local >= n_e) continue;
      float g = egate[e * B_DIM + m_local];
      size_t orow = (size_t)slotid[e * B_DIM + m_local] * O_DIM;
#pragma unroll
      for (int ni = 0; ni < 4; ni++) {
        int col = nt * BN + wn * 64 + ni * 16 + frow;
        out_buf[orow + col] = (acc[mi][ni][r] + b2[e * O_DIM + col]) * g;
      }
    }
  }
}

// ---------------- combine: y[b] = sum over 4 slots
__global__ __launch_bounds__(256) void combine_kernel(const float* __restrict__ out_buf,
                                                      float* __restrict__ y) {
  int idx = blockIdx.x * 256 + threadIdx.x;  // B*O/4 threads
  int b = idx >> 7;
  int o = (idx & 127) << 2;
  const float* base = out_buf + (size_t)b * K_TOP * O_DIM + o;
  float4 a0 = *(const float4*)(base);
  float4 a1 = *(const float4*)(base + O_DIM);
  float4 a2 = *(const float4*)(base + 2 * O_DIM);
  float4 a3 = *(const float4*)(base + 3 * O_DIM);
  float4 r;
  r.x = a0.x + a1.x + a2.x + a3.x;
  r.y = a0.y + a1.y + a2.y + a3.y;
  r.z = a0.z + a1.z + a2.z + a3.z;
  r.w = a0.w + a1.w + a2.w + a3.w;
  *(float4*)(y + (size_t)b * O_DIM + o) = r;
}

extern "C" void kernel_launch(void* const* d_in, const int* in_sizes, int n_in,
                              void* d_out, int out_size, void* d_ws, size_t ws_size,
                              hipStream_t stream) {
  (void)in_sizes; (void)n_in; (void)out_size; (void)ws_size;
  const float* query = (const float*)d_in[0];
  const float* x = (const float*)d_in[1];
  const float* wg = (const float*)d_in[2];
  const float* tg = (const float*)d_in[3];
  const float* W1 = (const float*)d_in[4];
  const float* b1 = (const float*)d_in[5];
  const float* W2 = (const float*)d_in[6];
  const float* b2 = (const float*)d_in[7];
  float* y = (float*)d_out;

  char* ws = (char*)d_ws;
  int* count = (int*)(ws + 0);                // 64 B
  int* offs = (int*)(ws + 128);               // 64 B
  int* rowlist = (int*)(ws + 256);            // 256 KB
  int* slotid = (int*)(ws + 262400);          // 256 KB
  float* egate = (float*)(ws + 524544);       // 256 KB
  int4* topk_e4 = (int4*)(ws + 786688);       // 64 KB
  float4* topk_g4 = (float4*)(ws + 852224);   // 64 KB
  short* h_buf = (short*)(ws + 1048576);      // 32 MB bf16 [16384][H]  (live gemm1->gemm2)
  short* w2t = (short*)(ws + 34603008);       // 16 MB bf16 [E][O][H]   (live ->gemm2)
  // region A: dead after gemm1, overlaid by out_buf
  short* x_bf = (short*)(ws + 51380224);      // 4 MB  bf16 [4096][512]
  short* w1t = (short*)(ws + 55574528);       // 16 MB bf16 [E][H][D]
  float* out_buf = (float*)(ws + 51380224);   // 32 MB f32 [16384][O]   (overlays region A)

  prep_gate_kernel<<<dim3(5120), 256, 0, stream>>>(x, query, wg, tg, W1, W2,
                                                   w1t, w2t, x_bf, topk_e4, topk_g4);
  csr_kernel<<<dim3(E_NUM), 1024, 0, stream>>>(topk_e4, topk_g4, count, offs,
                                               rowlist, slotid, egate,
                                               y + (size_t)B_DIM * O_DIM);
  gemm1_kernel<<<dim3(4096), 256, 0, stream>>>(x_bf, w1t, b1, count, offs, rowlist, h_buf);
  gemm2_kernel<<<dim3(2048), 256, 0, stream>>>(h_buf, w2t, b2, count, offs, slotid, egate,
                                               out_buf);
  combine_kernel<<<dim3(B_DIM * O_DIM / 4 / 256), 256, 0, stream>>>(out_buf, y);
}